// Round 7
// baseline (4982.015 us; speedup 1.0000x reference)
//
#include <hip/hip_runtime.h>
#include <hip/hip_fp16.h>

#define T_STEPS 512
#define BDIM 512
#define LDIM 512
#define FDIM 128

typedef _Float16 half8 __attribute__((ext_vector_type(8)));
typedef float f4_t __attribute__((ext_vector_type(4)));
typedef unsigned long long ull2 __attribute__((ext_vector_type(2)));

// workspace offsets (bytes), all 16B-aligned
#define OFF_WPERM   0u          // 2048*512*2   = 2097152
#define OFF_WDH     2097152u    // 128*512*2    = 131072
#define OFF_BCOMB   2228224u    // 2048*4       = 8192
#define OFF_HBUF0   2236416u    // 512*512*2    = 524288
#define OFF_HBUF1   2760704u    // 512*512*2
#define OFF_FLAGS   3284992u    // 8 g * 4 wv * 32 cb * 4B = 4096
// total ~3.3 MB

__device__ __forceinline__ float sigmoidf_(float x) { return 1.f / (1.f + __expf(-x)); }
__device__ __forceinline__ float tanhf_(float x) { return 1.f - 2.f / (__expf(2.f * x) + 1.f); }

// relaxed agent-scope ops: bypass L1/L2 to the device coherence point — no wb/inv fences.
// (validated on this HW: R3/R4 exchanged h cross-XCD through these and passed)
__device__ __forceinline__ unsigned long long aload64(const void* p) {
    return __hip_atomic_load((const unsigned long long*)p, __ATOMIC_RELAXED, __HIP_MEMORY_SCOPE_AGENT);
}
__device__ __forceinline__ void astore32(void* p, unsigned v) {
    __hip_atomic_store((unsigned*)p, v, __ATOMIC_RELAXED, __HIP_MEMORY_SCOPE_AGENT);
}

// ---------------- precompute: W_perm = permuted+swizzled fp16 of (W_hh + W_ih@W_dense), b_comb ----------------
// row pr = s*4+gate (s-major so MFMA C rows give lane-local i,f,g,o); element swizzle k ^ ((pr&7)<<6)
__global__ __launch_bounds__(256) void k_prep_w(
    const float* __restrict__ W_ih, const float* __restrict__ W_hh,
    const float* __restrict__ b_ih, const float* __restrict__ b_hh,
    const float* __restrict__ W_dense, const float* __restrict__ b_dense,
    _Float16* __restrict__ Wperm, float* __restrict__ bcomb)
{
    __shared__ float ih[FDIM];
    const int pr = blockIdx.x;            // 0..2047
    const int gate = pr & 3, sg = pr >> 2;
    const int j = gate * 512 + sg;        // original gate row
    const int tid = threadIdx.x;
    if (tid < FDIM) ih[tid] = W_ih[j * FDIM + tid];
    __syncthreads();
    const int k0 = tid * 2;
    float a0 = W_hh[(size_t)j * LDIM + k0];
    float a1 = W_hh[(size_t)j * LDIM + k0 + 1];
    for (int f = 0; f < FDIM; ++f) {
        const float w = ih[f];
        a0 += w * W_dense[f * LDIM + k0];
        a1 += w * W_dense[f * LDIM + k0 + 1];
    }
    const int s = (pr & 7) << 6;          // element-level XOR swizzle (k bits 6-8)
    Wperm[(size_t)pr * LDIM + (k0 ^ s)] = (_Float16)a0;
    Wperm[(size_t)pr * LDIM + (k0 ^ s) + 1] = (_Float16)a1;
    if (tid == 0) {
        float acc = b_ih[j] + b_hh[j];
        for (int f = 0; f < FDIM; ++f) acc += ih[f] * b_dense[f];
        bcomb[j] = acc;
    }
}

// ---------------- precompute: fp16 swizzled W_dense copy + fp16 swizzled h0 ----------------
__global__ __launch_bounds__(256) void k_prep_misc(
    const float* __restrict__ W_dense, const float* __restrict__ h0,
    _Float16* __restrict__ Wdh, _Float16* __restrict__ hbuf0)
{
    const int bid = blockIdx.x, tid = threadIdx.x;
    const int k0 = tid * 2;
    if (bid < FDIM) {
        const int f = bid; const int s = (f & 7) << 6;
        Wdh[f * LDIM + (k0 ^ s)] = (_Float16)W_dense[f * LDIM + k0];
        Wdh[f * LDIM + (k0 ^ s) + 1] = (_Float16)W_dense[f * LDIM + k0 + 1];
    } else {
        const int r = bid - FDIM; const int s = (r & 7) << 6;
        hbuf0[r * LDIM + (k0 ^ s)] = (_Float16)h0[r * LDIM + k0];
        hbuf0[r * LDIM + (k0 ^ s) + 1] = (_Float16)h0[r * LDIM + k0 + 1];
    }
}

// ---------------- persistent recurrence kernel: no LDS, no block barriers, quad-pipelined dataflow --------
// grid (32 col-blocks, 8 row-groups) = 256 blocks = 1/CU; 4 waves/block, wave = 16 batch rows.
// Wave (cb,g,wv): gates for 64 gate-cols (cb) x 16 rows, K=512 in 4 quads of 4 K-chunks (32 h-cols each).
// Per-quad flag gating (8 producer flags / quad); b-data + flags prefetched one quad ahead.
__global__ __launch_bounds__(256, 1) void k_persist(
    const _Float16* __restrict__ Wperm, const _Float16* __restrict__ Wdh,
    const float* __restrict__ bcomb, const float* __restrict__ bdense,
    const float* __restrict__ c0,
    _Float16* __restrict__ hb0, _Float16* __restrict__ hb1,
    float* __restrict__ out, unsigned* __restrict__ flags)
{
    const int cb = blockIdx.x;      // 0..31 gate-col block
    const int g = blockIdx.y;       // 0..7 row group
    const int tid = threadIdx.x;
    const int wv = tid >> 6, lane = tid & 63;
    const int lr = lane & 15, lh = lane >> 4;
    const int row = g * 64 + wv * 16 + lr;       // batch row this lane serves
    const int swz = (lr & 7) << 7;               // byte swizzle (row&7 == lr&7 for W and h rows)
    const int qs = cb >> 3;                      // starting quad: contains this block's own published cols

    // ---- one-time: A operands into registers, stored in rotated-quad order: i=j*4+cc ↔ chunk ((qs+j)&3)*4+cc
    half8 aA[4][16];                             // 256 VGPR: W gate rows, 4 m-tiles x 16 k-chunks
    half8 aD[16];                                // 64 VGPR: W_dense rows (lanes lr<4 valid)
    {
        const char* wbase = (const char*)Wperm + (size_t)cb * 65536;
        const int fd = cb * 4 + (lr & 3);
        const char* dbase = (const char*)Wdh + (size_t)fd * 1024;
        const int swD = (fd & 7) << 7;
        #pragma unroll
        for (int j = 0; j < 4; ++j) {
            #pragma unroll
            for (int cc = 0; cc < 4; ++cc) {
                const int kt = ((qs + j) & 3) * 4 + cc;
                const int kb = kt * 64 + lh * 16;
                const int i = j * 4 + cc;
                #pragma unroll
                for (int m = 0; m < 4; ++m)
                    aA[m][i] = *(const half8*)(wbase + (m * 16 + lr) * 1024 + (kb ^ swz));
                aD[i] = *(const half8*)(dbase + (kb ^ swD));
            }
        }
    }

    // ---- biases + c-state + dense bias in registers ----
    float bi[4], bf[4], bg[4], bo[4], creg[4];
    #pragma unroll
    for (int m = 0; m < 4; ++m) {
        const int sg = cb * 16 + m * 4 + lh;
        bi[m] = bcomb[0 * 512 + sg];
        bf[m] = bcomb[1 * 512 + sg];
        bg[m] = bcomb[2 * 512 + sg];
        bo[m] = bcomb[3 * 512 + sg];
        creg[m] = c0[(size_t)row * LDIM + sg];
    }
    float bd[4];
    #pragma unroll
    for (int j = 0; j < 4; ++j) bd[j] = bdense[cb * 4 + j];

    unsigned* fbase = flags + (g * 4 + wv) * 32; // this (g,wv) slice's 32 producer flags
    const size_t rowoff = (size_t)row * 1024;

    unsigned long long pf0, pf1, pf2, pf3;       // pending flag quad
    ull2 bq[4], bn[4];                           // current / next quad b-data

#define FISSUE(q) do { const int qq_ = (q) & 3;                      \
        pf0 = aload64(fbase + qq_ * 8 + 0);                          \
        pf1 = aload64(fbase + qq_ * 8 + 2);                          \
        pf2 = aload64(fbase + qq_ * 8 + 4);                          \
        pf3 = aload64(fbase + qq_ * 8 + 6); } while (0)

#define FCHECK(q, tw_) do { const int qq_ = (q) & 3;                 \
        for (;;) {                                                   \
            if ((unsigned)pf0 >= (tw_) && (unsigned)(pf0 >> 32) >= (tw_) && \
                (unsigned)pf1 >= (tw_) && (unsigned)(pf1 >> 32) >= (tw_) && \
                (unsigned)pf2 >= (tw_) && (unsigned)(pf2 >> 32) >= (tw_) && \
                (unsigned)pf3 >= (tw_) && (unsigned)(pf3 >> 32) >= (tw_)) break; \
            __builtin_amdgcn_s_sleep(1);                             \
            pf0 = aload64(fbase + qq_ * 8 + 0);                      \
            pf1 = aload64(fbase + qq_ * 8 + 2);                      \
            pf2 = aload64(fbase + qq_ * 8 + 4);                      \
            pf3 = aload64(fbase + qq_ * 8 + 6);                      \
        } } while (0)

    // address-dependency on checked flag values: forbids hoisting b-loads above their gate
#define BISSUE(q, dst) do { const int qq_ = (q) & 3;                 \
        const unsigned dep_ = (unsigned)(((pf0 | pf1 | pf2 | pf3) >> 63) & 1ull); \
        _Pragma("unroll")                                            \
        for (int cc_ = 0; cc_ < 4; ++cc_) {                          \
            const char* hp_ = hbase + rowoff + ((((qq_ * 4 + cc_) * 64 + lh * 16) ^ swz) + dep_); \
            dst[cc_].x = aload64(hp_);                               \
            dst[cc_].y = aload64(hp_ + 8); } } while (0)

    for (int t = 1; t <= T_STEPS; ++t) {
        const char* hbase = (const char*)(((t - 1) & 1) ? hb1 : hb0);
        char* hout = (char*)((t & 1) ? hb1 : hb0);
        const unsigned tw = (unsigned)(t - 1);

        f4_t acc[4] = {};
        f4_t accx = {};

        // prologue: gate + load quad qs; prefetch flags for qs+1
        FISSUE(qs); FCHECK(qs, tw); BISSUE(qs, bq);
        FISSUE(qs + 1);

        #pragma unroll
        for (int j = 0; j < 4; ++j) {
            if (j < 3) {
                FCHECK(qs + j + 1, tw);          // pf issued one iter ago; usually already set
                BISSUE(qs + j + 1, bn);          // b-latency hides under this quad's MFMAs
                if (j < 2) FISSUE(qs + j + 2);   // flag-latency hides under MFMAs too
            }
            #pragma unroll
            for (int cc = 0; cc < 4; ++cc) {
                const half8 b = __builtin_bit_cast(half8, bq[cc]);
                const int i = j * 4 + cc;
                acc[0] = __builtin_amdgcn_mfma_f32_16x16x32_f16(aA[0][i], b, acc[0], 0, 0, 0);
                acc[1] = __builtin_amdgcn_mfma_f32_16x16x32_f16(aA[1][i], b, acc[1], 0, 0, 0);
                acc[2] = __builtin_amdgcn_mfma_f32_16x16x32_f16(aA[2][i], b, acc[2], 0, 0, 0);
                acc[3] = __builtin_amdgcn_mfma_f32_16x16x32_f16(aA[3][i], b, acc[3], 0, 0, 0);
                accx   = __builtin_amdgcn_mfma_f32_16x16x32_f16(aD[i],    b, accx,   0, 0, 0);
            }
            if (j < 3) { bq[0] = bn[0]; bq[1] = bn[1]; bq[2] = bn[2]; bq[3] = bn[3]; }
        }

        // ---- cell update + packed h publish (relaxed agent 4B stores -> L3) ----
        #pragma unroll
        for (int m = 0; m < 4; ++m) {
            const int sg = cb * 16 + m * 4 + lh;
            const float iv = sigmoidf_(acc[m][0] + bi[m]);
            const float fv = sigmoidf_(acc[m][1] + bf[m]);
            const float gv = tanhf_(acc[m][2] + bg[m]);
            const float ov = sigmoidf_(acc[m][3] + bo[m]);
            const float cnew = fv * creg[m] + iv * gv;
            const float hnew = ov * tanhf_(cnew);
            creg[m] = cnew;
            const unsigned u = (unsigned)__builtin_bit_cast(unsigned short, (_Float16)hnew);
            const unsigned up = (unsigned)__shfl_xor((int)u, 16);   // partner col (lh^1)
            if ((lh & 1) == 0) {
                astore32(hout + rowoff + ((sg * 2) ^ ((row & 7) << 7)), u | (up << 16));
            }
        }

        // release: all h stores complete at coherence point, then flag (asm pins compiler order)
        asm volatile("s_waitcnt vmcnt(0)" ::: "memory");
        if (lane == 0) astore32(fbase + cb, (unsigned)t);

        // ---- x_{t-1} = dense(h_{t-1}) -> out[:, t-2, :] (fire-and-forget) ----
        if (t >= 2 && lh == 0) {
            float* o = &out[((size_t)row * T_STEPS + (t - 2)) * FDIM + cb * 4];
            o[0] = accx[0] + bd[0];
            o[1] = accx[1] + bd[1];
            o[2] = accx[2] + bd[2];
            o[3] = accx[3] + bd[3];
        }
    }

    // ---- epilogue: x_T = dense(h_T) -> out[:, T-1, :] (one step, simple per-quad gating) ----
    {
        const unsigned tw = (unsigned)T_STEPS;
        const char* hbase = (const char*)hb0;    // T even -> h_T in buf 0
        f4_t accx = {};
        #pragma unroll
        for (int j = 0; j < 4; ++j) {
            FISSUE(qs + j); FCHECK(qs + j, tw); BISSUE(qs + j, bq);
            #pragma unroll
            for (int cc = 0; cc < 4; ++cc) {
                const half8 b = __builtin_bit_cast(half8, bq[cc]);
                accx = __builtin_amdgcn_mfma_f32_16x16x32_f16(aD[j * 4 + cc], b, accx, 0, 0, 0);
            }
        }
        if (lh == 0) {
            float* o = &out[((size_t)row * T_STEPS + (T_STEPS - 1)) * FDIM + cb * 4];
            o[0] = accx[0] + bd[0];
            o[1] = accx[1] + bd[1];
            o[2] = accx[2] + bd[2];
            o[3] = accx[3] + bd[3];
        }
    }
#undef FISSUE
#undef FCHECK
#undef BISSUE
}

extern "C" void kernel_launch(void* const* d_in, const int* in_sizes, int n_in,
                              void* d_out, int out_size, void* d_ws, size_t ws_size,
                              hipStream_t stream)
{
    const float* h0      = (const float*)d_in[0];
    const float* c0      = (const float*)d_in[1];
    const float* W_ih    = (const float*)d_in[2];
    const float* W_hh    = (const float*)d_in[3];
    const float* b_ih    = (const float*)d_in[4];
    const float* b_hh    = (const float*)d_in[5];
    const float* W_dense = (const float*)d_in[6];
    const float* b_dense = (const float*)d_in[7];
    float* out = (float*)d_out;
    char* ws = (char*)d_ws;

    _Float16* Wperm = (_Float16*)(ws + OFF_WPERM);
    _Float16* Wdh   = (_Float16*)(ws + OFF_WDH);
    float*    bcomb = (float*)(ws + OFF_BCOMB);
    _Float16* hb0   = (_Float16*)(ws + OFF_HBUF0);
    _Float16* hb1   = (_Float16*)(ws + OFF_HBUF1);
    unsigned* flags = (unsigned*)(ws + OFF_FLAGS);

    hipMemsetAsync(flags, 0, 4096, stream);
    k_prep_w<<<2048, 256, 0, stream>>>(W_ih, W_hh, b_ih, b_hh, W_dense, b_dense, Wperm, bcomb);
    k_prep_misc<<<FDIM + BDIM, 256, 0, stream>>>(W_dense, h0, Wdh, hb0);
    k_persist<<<dim3(32, 8), 256, 0, stream>>>(Wperm, Wdh, bcomb, b_dense, c0, hb0, hb1, out, flags);
}